// Round 7
// baseline (204.820 us; speedup 1.0000x reference)
//
#include <hip/hip_runtime.h>

#define PL 128
#define STRIDE 64
#define WSZ 16

typedef float f32x4 __attribute__((ext_vector_type(4)));

// DIAGNOSTIC ROUND: same R6 kernel, launched twice.
//   pass 0: patches + adj broadcast (normal, correct output)
//   pass 1: adj broadcast ONLY, re-writing identical values (output unchanged)
// The marginal dur of pass 1 measures pure 512MB store throughput in situ,
// separating "fixed harness overhead" from "real store-BW ceiling".
__global__ __launch_bounds__(256) void fused_kernel(
    const float* __restrict__ I, const float* __restrict__ Q,
    const float* __restrict__ ew, float* __restrict__ out, int P,
    int do_patches)
{
    const int tid  = threadIdx.x;
    const int bid  = blockIdx.x;
    const int nblk = gridDim.x;
    const int lane = tid & 63;
    const int w    = tid >> 6;            // wave id 0..3

    // ---- Part A: patches [P,128,2] (8 MB) ----
    if (do_patches) {
        f32x4* pout = reinterpret_cast<f32x4*>(out);
        const int total = P * (PL / 2);   // one f32x4 covers t, t+1
        for (int idx = bid * 256 + tid; idx < total; idx += nblk * 256) {
            int p = idx >> 6;
            int t = (idx & 63) * 2;
            int src = p * STRIDE + t;
            f32x4 val = {I[src], Q[src], I[src + 1], Q[src + 1]};
            __builtin_nontemporal_store(val, &pout[idx]);
        }
    }

    // ---- Part B: this wave-span's 64 adj elements -> 16 f32x4 registers ----
    f32x4 v[16];
    const int rbase = w * 32 + (lane >> 5);
    const int j0    = (lane & 31) * 4;
#pragma unroll
    for (int u = 0; u < 16; ++u) {
        const int row = rbase + u * 2;
        f32x4 val = {0.f, 0.f, 0.f, 0.f};
#pragma unroll
        for (int c = 0; c < 4; ++c) {
            int j = j0 + c;
            int d = row - j; if (d < 0) d = -d;
            if (d > 0 && d <= WSZ) {
                val[c] = 1.0f / (1.0f + __expf(-ew[row * PL + j]));
            }
        }
        v[u] = val;
    }

    // ---- Part C: store-only broadcast, wave-contiguous 16 KB bursts ----
    f32x4* aout = reinterpret_cast<f32x4*>(out + (size_t)P * PL * 2);
    int p0 = bid * 4;
    int p1 = p0 + 4; if (p1 > P) p1 = P;
    for (int p = p0; p < p1; ++p) {
        f32x4* dst = aout + (size_t)p * (PL * PL / 4) + w * 1024 + lane;
#pragma unroll
        for (int u = 0; u < 16; ++u) {
            __builtin_nontemporal_store(v[u], &dst[u * 64]);
        }
    }
}

extern "C" void kernel_launch(void* const* d_in, const int* in_sizes, int n_in,
                              void* d_out, int out_size, void* d_ws, size_t ws_size,
                              hipStream_t stream) {
    const float* I  = (const float*)d_in[0];
    const float* Q  = (const float*)d_in[1];
    const float* ew = (const float*)d_in[2];
    float* out = (float*)d_out;

    const int n = in_sizes[0];
    const int P = (n - PL) / STRIDE + 1;   // 7811 for L=500000

    const int nblk = (P + 3) / 4;          // block b -> patches [4b, 4b+4)
    // pass 0: full output
    fused_kernel<<<nblk, 256, 0, stream>>>(I, Q, ew, out, P, 1);
    // pass 1: redundant identical re-write of adjs (marginal-time probe)
    fused_kernel<<<nblk, 256, 0, stream>>>(I, Q, ew, out, P, 0);
}

// Round 8
// 99.834 us; speedup vs baseline: 2.0516x; 2.0516x over previous
//
#include <hip/hip_runtime.h>

#define PL 128
#define STRIDE 64
#define WSZ 16

typedef float f32x4 __attribute__((ext_vector_type(4)));

// Fill-kernel replica: grid = 256 blocks (1 per CU), grid-stride sweep.
// Since stride T = 256*256 = 65536 f32x4 is a multiple of the patch size
// (4096 f32x4), each thread's within-patch offset q = idx0 & 4095 is
// loop-invariant:  chunk kk = bid & 15, slot = tid, patch ≡ bid>>4 (mod 16).
// So each thread stores ONE f32x4 register value for its entire sweep —
// VGPR ~16, loop = {addr add, store, cmp, branch}. The whole device marches
// one 1 MB window at a time in near-lockstep, replicating the 6.9 TB/s
// fillBufferAligned stream shape (256 sequential streams, normal stores).
__global__ __launch_bounds__(256) void fused_kernel(
    const float* __restrict__ I, const float* __restrict__ Q,
    const float* __restrict__ ew, float* __restrict__ out, int P)
{
    const int tid = threadIdx.x;
    const int bid = blockIdx.x;
    const unsigned T    = gridDim.x * 256u;     // 65536 f32x4 = 1 MB window
    const unsigned idx0 = bid * 256u + tid;

    // ---- Part A: patches [P,128,2] (8 MB) ----
    {
        f32x4* pout = reinterpret_cast<f32x4*>(out);
        const unsigned total = (unsigned)P * (PL / 2);   // f32x4 covers t,t+1
        for (unsigned idx = idx0; idx < total; idx += T) {
            int p = (int)(idx >> 6);
            int t = ((int)idx & 63) * 2;
            int src = p * STRIDE + t;
            f32x4 val = {I[src], Q[src], I[src + 1], Q[src + 1]};
            pout[idx] = val;
        }
    }

    // ---- Part B: this thread's single f32x4 of adj ----
    // element e = (kk*256 + tid)*4 + c -> row = kk*8 + (tid>>5), col = (tid&31)*4 + c
    const int kk  = bid & 15;
    const int row = kk * 8 + (tid >> 5);
    const int j0  = (tid & 31) * 4;
    f32x4 v = {0.f, 0.f, 0.f, 0.f};
#pragma unroll
    for (int c = 0; c < 4; ++c) {
        int j = j0 + c;
        int d = row - j; if (d < 0) d = -d;
        if (d > 0 && d <= WSZ) {
            v[c] = 1.0f / (1.0f + __expf(-ew[row * PL + j]));
        }
    }

    // ---- Part C: device-lockstep sweep; thread's target offset is invariant ----
    f32x4* aout = reinterpret_cast<f32x4*>(out + (size_t)P * PL * 2);
    const unsigned M = (unsigned)P * (PL * PL / 4);      // 31,993,856 for P=7811
    for (unsigned m = idx0; m < M; m += T) {
        aout[m] = v;
    }
}

extern "C" void kernel_launch(void* const* d_in, const int* in_sizes, int n_in,
                              void* d_out, int out_size, void* d_ws, size_t ws_size,
                              hipStream_t stream) {
    const float* I  = (const float*)d_in[0];
    const float* Q  = (const float*)d_in[1];
    const float* ew = (const float*)d_in[2];
    float* out = (float*)d_out;

    const int n = in_sizes[0];
    const int P = (n - PL) / STRIDE + 1;   // 7811 for L=500000

    // 256 blocks = 1 per CU; MUST be a multiple of 16 for the invariant-offset
    // mapping (T % 4096 == 0) and covers all (patch mod 16, chunk) pairs.
    fused_kernel<<<256, 256, 0, stream>>>(I, Q, ew, out, P);
}